// Round 1
// baseline (2221.450 us; speedup 1.0000x reference)
//
#include <hip/hip_runtime.h>
#include <math.h>

#define L 32768
#define C 256
#define QD 512
#define SCALE (1.0f/16.0f)

// ---------------------------------------------------------------------------
// Generic fp32 GEMM: y[m,l] = sum_c W[m,c] * x[c,l] + b[m]   (optionally * mask[l])
// W: [M,K] row-major, x: [K,L] row-major, y: [M,L] row-major.
// Tile 64x64, K-chunk 32, 256 threads, 16 outputs/thread.
// ---------------------------------------------------------------------------
__global__ __launch_bounds__(256) void gemm_fp32(
    const float* __restrict__ W, const float* __restrict__ bias,
    const float* __restrict__ x, float* __restrict__ y,
    const float* __restrict__ mask, int K)
{
    __shared__ float sW[32][65];
    __shared__ float sX[32][66];
    const int t  = threadIdx.x;
    const int l0 = blockIdx.x * 64;
    const int m0 = blockIdx.y * 64;
    const int tx = t & 15;   // l-group
    const int ty = t >> 4;   // m-group
    float acc[4][4] = {};

    for (int k0 = 0; k0 < K; k0 += 32) {
        {
            const int kk = t & 31, mb = t >> 5;   // mb in [0,8)
            #pragma unroll
            for (int i = 0; i < 8; i++)
                sW[kk][mb + 8*i] = W[(size_t)(m0 + mb + 8*i) * K + k0 + kk];
            const int ll = t & 63, kb = t >> 6;   // kb in [0,4)
            #pragma unroll
            for (int i = 0; i < 8; i++)
                sX[kb + 4*i][ll] = x[(size_t)(k0 + kb + 4*i) * L + l0 + ll];
        }
        __syncthreads();
        #pragma unroll
        for (int kk = 0; kk < 32; kk++) {
            float a[4], b[4];
            #pragma unroll
            for (int i = 0; i < 4; i++) a[i] = sW[kk][ty + 16*i];
            #pragma unroll
            for (int j = 0; j < 4; j++) b[j] = sX[kk][tx + 16*j];
            #pragma unroll
            for (int i = 0; i < 4; i++)
                #pragma unroll
                for (int j = 0; j < 4; j++)
                    acc[i][j] += a[i] * b[j];
        }
        __syncthreads();
    }

    #pragma unroll
    for (int i = 0; i < 4; i++) {
        const int m  = m0 + ty + 16*i;
        const float bb = bias[m];
        #pragma unroll
        for (int j = 0; j < 4; j++) {
            const int l = l0 + tx + 16*j;
            float val = acc[i][j] + bb;
            if (mask) val *= mask[l];
            y[(size_t)m * L + l] = val;
        }
    }
}

// ---------------------------------------------------------------------------
// Fused sliding-window attention for a tile of 16 consecutive queries.
// Query p attends keys a in [p-256, p+255] clipped to [0,L).
// Union window for the tile: aa in [0, 527), indexed against abase = p0-256.
// Phases: (1) energy into LDS e[16][576], (2) exact masked softmax,
//         (3) PV + ReLU -> ao[c][p].
// Masked-column 1e-6 softmax contributions are dropped (rel err ~1e-6).
// ---------------------------------------------------------------------------
__global__ __launch_bounds__(256) void attn_fp32(
    const float* __restrict__ q, const float* __restrict__ k,
    const float* __restrict__ v, const float* __restrict__ mask,
    float* __restrict__ ao)
{
    __shared__ float e[16][576];     // 36.9 KB  energy -> softmax weights
    __shared__ float sq[256][17];    // 17.4 KB  q tile [c][i]
    __shared__ float sk[32][65];     //  8.3 KB  k/v staging chunk
    __shared__ float rbuf[16][17];   //  1.1 KB  reductions
    __shared__ float invD[16];

    const int t     = threadIdx.x;
    const int p0    = blockIdx.x * 16;
    const int abase = p0 - 256;

    // ---- stage q tile: sq[c][i] = q[c, p0+i] ----
    {
        const int i = t & 15, cb = t >> 4;
        #pragma unroll
        for (int it = 0; it < 16; it++) {
            const int c = cb + 16*it;
            sq[c][i] = q[(size_t)c * L + p0 + i];
        }
    }
    __syncthreads();

    // ---- energy: e[i][aa] = scale * sum_c q[c,p0+i] * k[c,abase+aa] ----
    const int jl = t & 63;   // key within 64-chunk
    const int ig = t >> 6;   // i = ig + 4*m
    for (int ac = 0; ac < 9; ac++) {
        float acc[4] = {0.f, 0.f, 0.f, 0.f};
        for (int cc = 0; cc < 8; cc++) {
            {
                const int jj = t & 63, cb2 = t >> 6;
                const int a2 = abase + ac*64 + jj;
                const bool ok = (a2 >= 0) && (a2 < L);
                #pragma unroll
                for (int mm = 0; mm < 8; mm++) {
                    const int c = cc*32 + cb2 + 4*mm;
                    sk[cb2 + 4*mm][jj] = ok ? k[(size_t)c * L + a2] : 0.0f;
                }
            }
            __syncthreads();
            #pragma unroll 8
            for (int c = 0; c < 32; c++) {
                const float kv = sk[c][jl];
                #pragma unroll
                for (int m = 0; m < 4; m++)
                    acc[m] += sq[cc*32 + c][ig + 4*m] * kv;
            }
            __syncthreads();
        }
        #pragma unroll
        for (int m = 0; m < 4; m++)
            e[ig + 4*m][ac*64 + jl] = acc[m] * SCALE;
    }
    __syncthreads();

    // ---- softmax over band aa in [i, i+512) ----
    {
        const int r    = t >> 4;   // query row
        const int lane = t & 15;
        float pmax = -1e30f;
        for (int s = 0; s < 32; s++) {
            const int aa = r + lane + 16*s;
            const int a  = abase + aa;
            const float m = (a >= 0 && a < L) ? mask[a] : 0.0f;
            if (m > 0.0f) pmax = fmaxf(pmax, e[r][aa]);
        }
        rbuf[r][lane] = pmax;
        __syncthreads();
        float M = -1e30f;
        #pragma unroll
        for (int u = 0; u < 16; u++) M = fmaxf(M, rbuf[r][u]);
        __syncthreads();
        float psum = 0.0f;
        for (int s = 0; s < 32; s++) {
            const int aa = r + lane + 16*s;
            const int a  = abase + aa;
            const float m = (a >= 0 && a < L) ? mask[a] : 0.0f;
            float w = 0.0f;
            if (m > 0.0f) w = m * expf(e[r][aa] - M);
            e[r][aa] = w;
            psum += w;
        }
        rbuf[r][lane] = psum;
        __syncthreads();
        float D = 0.0f;
        #pragma unroll
        for (int u = 0; u < 16; u++) D += rbuf[r][u];
        if (lane == 0) invD[r] = (D > 0.0f) ? (1.0f / D) : 0.0f;
    }
    __syncthreads();

    // ---- PV + ReLU: ao[c, p0+i] = relu( (1/D_i) * sum_aa w[i][aa]*v[c,abase+aa] )
    {
        const int cl = t & 31;   // c within 32-chunk
        const int ih = t >> 5;   // i in {ih, ih+8}
        const int i0 = ih, i1 = ih + 8;
        for (int cc = 0; cc < 8; cc++) {
            float acc0 = 0.0f, acc1 = 0.0f;
            for (int ac = 0; ac < 9; ac++) {
                {
                    const int jj = t & 63, cb2 = t >> 6;
                    const int a2 = abase + ac*64 + jj;
                    const bool ok = (a2 >= 0) && (a2 < L);
                    #pragma unroll
                    for (int mm = 0; mm < 8; mm++) {
                        const int c = cc*32 + cb2 + 4*mm;
                        sk[cb2 + 4*mm][jj] = ok ? v[(size_t)c * L + a2] : 0.0f;
                    }
                }
                __syncthreads();
                #pragma unroll 4
                for (int j2 = 0; j2 < 64; j2++) {
                    const int aa = ac*64 + j2;
                    const float vv = sk[cl][j2];
                    const float w0 = ((unsigned)(aa - i0) < 512u) ? e[i0][aa] : 0.0f;
                    const float w1 = ((unsigned)(aa - i1) < 512u) ? e[i1][aa] : 0.0f;
                    acc0 += vv * w0;
                    acc1 += vv * w1;
                }
                __syncthreads();
            }
            const int c = cc*32 + cl;
            const float o0 = fmaxf(acc0 * invD[i0], 0.0f);
            const float o1 = fmaxf(acc1 * invD[i1], 0.0f);
            ao[(size_t)c * L + p0 + i0] = o0;
            ao[(size_t)c * L + p0 + i1] = o1;
        }
    }
}

extern "C" void kernel_launch(void* const* d_in, const int* in_sizes, int n_in,
                              void* d_out, int out_size, void* d_ws, size_t ws_size,
                              hipStream_t stream)
{
    const float* x1   = (const float*)d_in[0];
    // d_in[1] = x2 (unused by reference)
    const float* mask = (const float*)d_in[2];
    const float* Wq   = (const float*)d_in[3];
    const float* bq   = (const float*)d_in[4];
    const float* Wk   = (const float*)d_in[5];
    const float* bk   = (const float*)d_in[6];
    const float* Wv   = (const float*)d_in[7];
    const float* bv   = (const float*)d_in[8];
    const float* Wo   = (const float*)d_in[9];
    const float* bo   = (const float*)d_in[10];
    float* out = (float*)d_out;

    // workspace layout (floats): q | k | v | ao  -> 4 * 256 * 32768 * 4B = 128 MB
    float* q  = (float*)d_ws;
    float* k  = q  + (size_t)C * L;
    float* v  = k  + (size_t)C * L;
    float* ao = v  + (size_t)C * L;

    dim3 blk(256);
    gemm_fp32<<<dim3(L/64, C/64),  blk, 0, stream>>>(Wq, bq, x1, q,  nullptr, QD);
    gemm_fp32<<<dim3(L/64, C/64),  blk, 0, stream>>>(Wk, bk, x1, k,  nullptr, QD);
    gemm_fp32<<<dim3(L/64, C/64),  blk, 0, stream>>>(Wv, bv, x1, v,  nullptr, QD);
    attn_fp32<<<dim3(L/16),        blk, 0, stream>>>(q, k, v, mask, ao);
    gemm_fp32<<<dim3(L/64, QD/64), blk, 0, stream>>>(Wo, bo, ao, out, mask, C);
}

// Round 2
// 832.649 us; speedup vs baseline: 2.6679x; 2.6679x over previous
//
#include <hip/hip_runtime.h>
#include <hip/hip_bf16.h>
#include <math.h>

#define L 32768
#define C 256
#define QD 512
#define SCALE (1.0f/16.0f)

typedef __hip_bfloat16 bf16;
typedef short v8s __attribute__((ext_vector_type(8)));
typedef float v4f __attribute__((ext_vector_type(4)));

// ---------------------------------------------------------------------------
// fp32 GEMM: y[m,l] = sum_c W[m,c]*x[c,l] + b[m]  (optional *mask[l]).
// bf16_out!=0 -> store bf16, else fp32. Tile 64x64, K-chunk 32.
// ---------------------------------------------------------------------------
__global__ __launch_bounds__(256) void gemm_tile(
    const float* __restrict__ W, const float* __restrict__ bias,
    const float* __restrict__ x, void* __restrict__ y,
    const float* __restrict__ mask, int K, int bf16_out)
{
    __shared__ float sW[32][65];
    __shared__ float sX[32][66];
    const int t  = threadIdx.x;
    const int l0 = blockIdx.x * 64;
    const int m0 = blockIdx.y * 64;
    const int tx = t & 15;
    const int ty = t >> 4;
    float acc[4][4] = {};

    for (int k0 = 0; k0 < K; k0 += 32) {
        {
            const int kk = t & 31, mb = t >> 5;
            #pragma unroll
            for (int i = 0; i < 8; i++)
                sW[kk][mb + 8*i] = W[(size_t)(m0 + mb + 8*i) * K + k0 + kk];
            const int ll = t & 63, kb = t >> 6;
            #pragma unroll
            for (int i = 0; i < 8; i++)
                sX[kb + 4*i][ll] = x[(size_t)(k0 + kb + 4*i) * L + l0 + ll];
        }
        __syncthreads();
        #pragma unroll
        for (int kk = 0; kk < 32; kk++) {
            float a[4], b[4];
            #pragma unroll
            for (int i = 0; i < 4; i++) a[i] = sW[kk][ty + 16*i];
            #pragma unroll
            for (int j = 0; j < 4; j++) b[j] = sX[kk][tx + 16*j];
            #pragma unroll
            for (int i = 0; i < 4; i++)
                #pragma unroll
                for (int j = 0; j < 4; j++)
                    acc[i][j] += a[i] * b[j];
        }
        __syncthreads();
    }

    #pragma unroll
    for (int i = 0; i < 4; i++) {
        const int m  = m0 + ty + 16*i;
        const float bb = bias[m];
        #pragma unroll
        for (int j = 0; j < 4; j++) {
            const int l = l0 + tx + 16*j;
            float val = acc[i][j] + bb;
            if (mask) val *= mask[l];
            if (bf16_out) ((bf16*)y)[(size_t)m * L + l] = __float2bfloat16(val);
            else         ((float*)y)[(size_t)m * L + l] = val;
        }
    }
}

// ---------------------------------------------------------------------------
// bf16 transpose: in [C][L] -> out [L][C], 64x64 tiles through LDS.
// ---------------------------------------------------------------------------
__global__ __launch_bounds__(256) void transpose_cb(
    const short* __restrict__ in, short* __restrict__ out)
{
    __shared__ short st[64*72];
    const int t  = threadIdx.x;
    const int l0 = blockIdx.x * 64, c0 = blockIdx.y * 64;
    #pragma unroll
    for (int i = 0; i < 2; i++) {
        int v = i*256 + t;
        int c = v >> 3, l8 = (v & 7) << 3;
        v8s val = *(const v8s*)(in + (size_t)(c0 + c) * L + l0 + l8);
        #pragma unroll
        for (int j = 0; j < 8; j++) st[(l8 + j)*72 + c] = val[j];
    }
    __syncthreads();
    #pragma unroll
    for (int i = 0; i < 2; i++) {
        int v = i*256 + t;
        int l = v >> 3, c8 = (v & 7) << 3;
        *(v8s*)(out + (size_t)(l0 + l) * C + c0 + c8) = *(const v8s*)&st[l*72 + c8];
    }
}

// ---------------------------------------------------------------------------
// Flash-style sliding-window attention, bf16 MFMA 16x16x32, fp32 softmax.
// Block = 64 queries, 4 waves x 16 queries. Keys: 9 chunks of 64 covering
// [p0-256, p0+319]. qT,kT: [L][C] bf16; vB: [C][L] bf16; ao: [C][L] fp32.
// ---------------------------------------------------------------------------
__global__ __launch_bounds__(256, 2) void attn_mfma(
    const bf16* __restrict__ qT, const bf16* __restrict__ kT,
    const bf16* __restrict__ vB, const float* __restrict__ mask,
    float* __restrict__ ao)
{
    __shared__ short sK [64*264];   // [key][c]   33.8 KB
    __shared__ short sVt[256*72];   // [c][key]   36.9 KB
    __shared__ short sP [4][16*72]; // per-wave P [q][key]  9.2 KB

    const int t    = threadIdx.x;
    const int w    = t >> 6;
    const int lane = t & 63;
    const int col  = lane & 15;
    const int quad = lane >> 4;
    const int p0   = blockIdx.x * 64;
    const int abase = p0 - 256;

    // Q fragments (A-operand: m=col=query-in-wave, k=channel)
    v8s qf[8];
    {
        const short* qp = (const short*)qT + (size_t)(p0 + w*16 + col) * C + quad*8;
        #pragma unroll
        for (int ks = 0; ks < 8; ks++) qf[ks] = *(const v8s*)(qp + ks*32);
    }

    v4f oacc[16];
    #pragma unroll
    for (int i = 0; i < 16; i++) oacc[i] = (v4f){0.f, 0.f, 0.f, 0.f};
    float mrow[4] = {-1e30f, -1e30f, -1e30f, -1e30f};
    float lrow[4] = {0.f, 0.f, 0.f, 0.f};

    for (int ch = 0; ch < 9; ch++) {
        const int a0 = abase + ch*64;
        __syncthreads();
        // ---- stage K chunk: sK[key][c] from kT rows ----
        #pragma unroll
        for (int i = 0; i < 8; i++) {
            int idx = i*256 + t;
            int r = idx >> 5, cb = (idx & 31) << 3;
            int a = a0 + r;
            v8s val = {0,0,0,0,0,0,0,0};
            if (a >= 0 && a < L)
                val = *(const v8s*)((const short*)kT + (size_t)a * C + cb);
            *(v8s*)&sK[r*264 + cb] = val;
        }
        // ---- stage V chunk transposed: sVt[c][key] from vB rows ----
        if (a0 >= 0 && a0 + 63 < L) {
            #pragma unroll
            for (int i = 0; i < 8; i++) {
                int idx = i*256 + t;
                int c = idx >> 3, kb = (idx & 7) << 3;
                *(v8s*)&sVt[c*72 + kb] =
                    *(const v8s*)((const short*)vB + (size_t)c * L + a0 + kb);
            }
        } else {
            #pragma unroll
            for (int i = 0; i < 8; i++) {
                int idx = i*256 + t;
                int c = idx >> 3, kb = (idx & 7) << 3;
                v8s val;
                #pragma unroll
                for (int j = 0; j < 8; j++) {
                    int a = a0 + kb + j;
                    val[j] = (a >= 0 && a < L)
                        ? ((const short*)vB)[(size_t)c * L + a] : (short)0;
                }
                *(v8s*)&sVt[c*72 + kb] = val;
            }
        }
        __syncthreads();

        // ---- QK^T: E[q][key] per wave: 4 key-tiles x K=256 ----
        v4f e[4];
        #pragma unroll
        for (int nt = 0; nt < 4; nt++) {
            v4f acc = {0.f, 0.f, 0.f, 0.f};
            const short* kp = &sK[(nt*16 + col)*264 + quad*8];
            #pragma unroll
            for (int ks = 0; ks < 8; ks++) {
                v8s bfrag = *(const v8s*)(kp + ks*32);
                acc = __builtin_amdgcn_mfma_f32_16x16x32_bf16(qf[ks], bfrag, acc, 0, 0, 0);
            }
            e[nt] = acc;
        }

        // ---- mask + scale + per-row max (row q = quad*4+r) ----
        float cmax[4] = {-1e30f, -1e30f, -1e30f, -1e30f};
        #pragma unroll
        for (int nt = 0; nt < 4; nt++) {
            int a  = a0 + nt*16 + col;
            int aa = ch*64 + nt*16 + col;
            float mval = (a >= 0 && a < L) ? mask[a] : 0.f;
            #pragma unroll
            for (int r = 0; r < 4; r++) {
                int rel = aa - (w*16 + quad*4 + r);
                bool valid = ((unsigned)rel < 512u) && (mval > 0.f);
                float ev = valid ? e[nt][r] * SCALE : -1e30f;
                e[nt][r] = ev;
                cmax[r] = fmaxf(cmax[r], ev);
            }
        }
        #pragma unroll
        for (int off = 1; off < 16; off <<= 1) {
            #pragma unroll
            for (int r = 0; r < 4; r++)
                cmax[r] = fmaxf(cmax[r], __shfl_xor(cmax[r], off));
        }

        float alpha[4];
        #pragma unroll
        for (int r = 0; r < 4; r++) {
            float mnew = fmaxf(mrow[r], cmax[r]);
            alpha[r] = __expf(mrow[r] - mnew);
            mrow[r] = mnew;
        }

        // ---- P = exp(E - m), row sums, write P to wave-private LDS ----
        float psum[4] = {0.f, 0.f, 0.f, 0.f};
        bf16* sPw = (bf16*)sP[w];
        #pragma unroll
        for (int nt = 0; nt < 4; nt++) {
            #pragma unroll
            for (int r = 0; r < 4; r++) {
                float ev = e[nt][r];
                float p = (ev > -9e29f) ? __expf(ev - mrow[r]) : 0.f;
                psum[r] += p;
                sPw[(quad*4 + r)*72 + nt*16 + col] = __float2bfloat16(p);
            }
        }
        #pragma unroll
        for (int off = 1; off < 16; off <<= 1) {
            #pragma unroll
            for (int r = 0; r < 4; r++)
                psum[r] += __shfl_xor(psum[r], off);
        }
        #pragma unroll
        for (int r = 0; r < 4; r++) lrow[r] = lrow[r]*alpha[r] + psum[r];

        // ---- broadcast alpha for q=col; rescale O ----
        {
            int src = (col >> 2) << 4;
            float a0b = __shfl(alpha[0], src);
            float a1b = __shfl(alpha[1], src);
            float a2b = __shfl(alpha[2], src);
            float a3b = __shfl(alpha[3], src);
            int rr = col & 3;
            float aO = (rr == 0) ? a0b : (rr == 1) ? a1b : (rr == 2) ? a2b : a3b;
            #pragma unroll
            for (int i = 0; i < 16; i++) {
                oacc[i][0] *= aO; oacc[i][1] *= aO;
                oacc[i][2] *= aO; oacc[i][3] *= aO;
            }
        }

        // ---- PV: O^T[c][q] += V'[c][a] * P^T[a][q] ----
        {
            const short* sPws = (const short*)sP[w];
            v8s pf0 = *(const v8s*)&sPws[col*72 + quad*8];
            v8s pf1 = *(const v8s*)&sPws[col*72 + quad*8 + 32];
            #pragma unroll
            for (int ct = 0; ct < 16; ct++) {
                const short* vp = &sVt[(ct*16 + col)*72 + quad*8];
                v8s vf0 = *(const v8s*)vp;
                v8s vf1 = *(const v8s*)(vp + 32);
                oacc[ct] = __builtin_amdgcn_mfma_f32_16x16x32_bf16(vf0, pf0, oacc[ct], 0, 0, 0);
                oacc[ct] = __builtin_amdgcn_mfma_f32_16x16x32_bf16(vf1, pf1, oacc[ct], 0, 0, 0);
            }
        }
    }

    // ---- epilogue: normalize, ReLU, store fp32 [c][l] ----
    {
        int src = (col >> 2) << 4;
        float l0b = __shfl(lrow[0], src);
        float l1b = __shfl(lrow[1], src);
        float l2b = __shfl(lrow[2], src);
        float l3b = __shfl(lrow[3], src);
        int rr = col & 3;
        float lO = (rr == 0) ? l0b : (rr == 1) ? l1b : (rr == 2) ? l2b : l3b;
        float inv = (lO > 0.f) ? 1.f / lO : 0.f;
        const int qg = p0 + w*16 + col;
        #pragma unroll
        for (int ct = 0; ct < 16; ct++) {
            #pragma unroll
            for (int r = 0; r < 4; r++) {
                int c = ct*16 + quad*4 + r;
                ao[(size_t)c * L + qg] = fmaxf(oacc[ct][r] * inv, 0.f);
            }
        }
    }
}

extern "C" void kernel_launch(void* const* d_in, const int* in_sizes, int n_in,
                              void* d_out, int out_size, void* d_ws, size_t ws_size,
                              hipStream_t stream)
{
    const float* x1   = (const float*)d_in[0];
    const float* mask = (const float*)d_in[2];
    const float* Wq   = (const float*)d_in[3];
    const float* bq   = (const float*)d_in[4];
    const float* Wk   = (const float*)d_in[5];
    const float* bk   = (const float*)d_in[6];
    const float* Wv   = (const float*)d_in[7];
    const float* bv   = (const float*)d_in[8];
    const float* Wo   = (const float*)d_in[9];
    const float* bo   = (const float*)d_in[10];
    float* out = (float*)d_out;

    // ws layout: qC,kC,vB bf16[C][L] | qT,kT bf16[L][C] | ao fp32[C][L]  = 112 MB
    bf16* qC = (bf16*)d_ws;
    bf16* kC = qC + (size_t)C * L;
    bf16* vB = kC + (size_t)C * L;
    bf16* qT = vB + (size_t)C * L;
    bf16* kT = qT + (size_t)L * C;
    float* ao = (float*)(kT + (size_t)L * C);

    dim3 blk(256);
    gemm_tile<<<dim3(L/64, C/64), blk, 0, stream>>>(Wq, bq, x1, qC, nullptr, QD, 1);
    gemm_tile<<<dim3(L/64, C/64), blk, 0, stream>>>(Wk, bk, x1, kC, nullptr, QD, 1);
    gemm_tile<<<dim3(L/64, C/64), blk, 0, stream>>>(Wv, bv, x1, vB, nullptr, QD, 1);
    transpose_cb<<<dim3(L/64, C/64), blk, 0, stream>>>((const short*)qC, (short*)qT);
    transpose_cb<<<dim3(L/64, C/64), blk, 0, stream>>>((const short*)kC, (short*)kT);
    attn_mfma<<<dim3(L/64), blk, 0, stream>>>(qT, kT, vB, mask, ao);
    gemm_tile<<<dim3(L/64, QD/64), blk, 0, stream>>>(Wo, bo, ao, out, mask, C, 0);
}

// Round 3
// 304.538 us; speedup vs baseline: 7.2945x; 2.7341x over previous
//
#include <hip/hip_runtime.h>
#include <hip/hip_bf16.h>
#include <math.h>

#define L 32768
#define C 256
#define QD 512
#define SCALE (1.0f/16.0f)

typedef __hip_bfloat16 bf16;
typedef short v8s __attribute__((ext_vector_type(8)));
typedef short v4s __attribute__((ext_vector_type(4)));
typedef float v4f __attribute__((ext_vector_type(4)));

__device__ __forceinline__ void ldst16(void* lds, const void* g) {
    __builtin_amdgcn_global_load_lds(
        (const __attribute__((address_space(1))) unsigned int*)g,
        (__attribute__((address_space(3))) unsigned int*)lds, 16, 0, 0);
}
__device__ __forceinline__ short bfbits(float x) {
    bf16 h = __float2bfloat16(x);
    return *reinterpret_cast<short*>(&h);
}

// ---------------------------------------------------------------------------
// prep: pack Wq/Wk/Wv -> Wall bf16 [768][512]; Wo -> Wob bf16 [512][256];
// biases -> ball fp32 [768].
// ---------------------------------------------------------------------------
__global__ __launch_bounds__(256) void prep(
    const float* __restrict__ Wq, const float* __restrict__ Wk,
    const float* __restrict__ Wv, const float* __restrict__ bq,
    const float* __restrict__ bk, const float* __restrict__ bv,
    const float* __restrict__ Wo,
    bf16* __restrict__ Wall, bf16* __restrict__ Wob, float* __restrict__ ball)
{
    int i = blockIdx.x * 256 + threadIdx.x;
    if (i < 768*512) {
        int row = i >> 9, idx = i & 511;
        const float* src = row < 256 ? Wq : row < 512 ? Wk : Wv;
        Wall[i] = __float2bfloat16(src[(row & 255) * 512 + idx]);
    } else if (i < 768*512 + 512*256) {
        int j = i - 768*512;
        Wob[j] = __float2bfloat16(Wo[j]);
    } else if (i < 768*512 + 512*256 + 768) {
        int j = i - 768*512 - 512*256;
        ball[j] = j < 256 ? bq[j] : j < 512 ? bk[j - 256] : bv[j - 512];
    }
}

// ---------------------------------------------------------------------------
// convt: x1 fp32 [512][L] -> x1T bf16 [L][512], 64x64 tiles via LDS.
// ---------------------------------------------------------------------------
__global__ __launch_bounds__(256) void convt(
    const float* __restrict__ x, short* __restrict__ xT)
{
    __shared__ short st[64*72];
    const int t = threadIdx.x;
    const int l0 = blockIdx.x * 64, c0 = blockIdx.y * 64;
    #pragma unroll
    for (int i = 0; i < 2; i++) {
        int v = i*256 + t;
        int c = v >> 3, l8 = (v & 7) << 3;
        const float* p = x + (size_t)(c0 + c) * L + l0 + l8;
        float4 f0 = *(const float4*)p;
        float4 f1 = *(const float4*)(p + 4);
        bf16* stb = (bf16*)st;
        stb[(l8+0)*72 + c] = __float2bfloat16(f0.x);
        stb[(l8+1)*72 + c] = __float2bfloat16(f0.y);
        stb[(l8+2)*72 + c] = __float2bfloat16(f0.z);
        stb[(l8+3)*72 + c] = __float2bfloat16(f0.w);
        stb[(l8+4)*72 + c] = __float2bfloat16(f1.x);
        stb[(l8+5)*72 + c] = __float2bfloat16(f1.y);
        stb[(l8+6)*72 + c] = __float2bfloat16(f1.z);
        stb[(l8+7)*72 + c] = __float2bfloat16(f1.w);
    }
    __syncthreads();
    #pragma unroll
    for (int i = 0; i < 2; i++) {
        int v = i*256 + t;
        int l = v >> 3, c8 = (v & 7) << 3;
        *(v8s*)(xT + (size_t)(l0 + l) * QD + c0 + c8) = *(const v8s*)&st[l*72 + c8];
    }
}

// ---------------------------------------------------------------------------
// Fused QKV GEMM (m97-style): Y[768][L] = Wall[768][512] . x1T[L][512]^T.
// 128x128 tile, BK=32, global_load_lds staging, 4 waves x (64x64).
// Epilogue: my 0..1 -> qT [L][256] (transposed), 2..3 -> kT, 4..5 -> vB [C][L].
// ---------------------------------------------------------------------------
__global__ __launch_bounds__(256) void qkv_gemm(
    const bf16* __restrict__ A, const bf16* __restrict__ B,
    const float* __restrict__ ball,
    bf16* __restrict__ qT, bf16* __restrict__ kT, bf16* __restrict__ vB)
{
    __shared__ short sA[128*32];    // 8 KB  [m][k]
    __shared__ short sB[128*32];    // 8 KB  [n][k]
    __shared__ short sE[128*136];   // 34 KB epilogue staging

    const int t    = threadIdx.x;
    const int lane = t & 63;
    const int w    = t >> 6;
    const int wm   = w & 1, wn = w >> 1;
    const int col  = lane & 15, quad = lane >> 4;
    const int n0   = blockIdx.x * 128;
    const int my   = blockIdx.y;
    const int m0   = my * 128;

    v4f acc[4][4];
    #pragma unroll
    for (int i = 0; i < 4; i++)
        #pragma unroll
        for (int j = 0; j < 4; j++) acc[i][j] = (v4f){0.f,0.f,0.f,0.f};

    for (int k0 = 0; k0 < QD; k0 += 32) {
        #pragma unroll
        for (int j = 0; j < 2; j++) {
            int idx = j*256 + t;
            int m = idx >> 2, k8 = (idx & 3) << 3;
            ldst16(&sA[idx*8], A + (size_t)(m0 + m) * QD + k0 + k8);
        }
        #pragma unroll
        for (int j = 0; j < 2; j++) {
            int idx = j*256 + t;
            int n = idx >> 2, k8 = (idx & 3) << 3;
            ldst16(&sB[idx*8], B + (size_t)(n0 + n) * QD + k0 + k8);
        }
        __syncthreads();
        v8s af[4], bf[4];
        #pragma unroll
        for (int mt = 0; mt < 4; mt++)
            af[mt] = *(const v8s*)&sA[(wm*64 + mt*16 + col)*32 + quad*8];
        #pragma unroll
        for (int nt = 0; nt < 4; nt++)
            bf[nt] = *(const v8s*)&sB[(wn*64 + nt*16 + col)*32 + quad*8];
        #pragma unroll
        for (int mt = 0; mt < 4; mt++)
            #pragma unroll
            for (int nt = 0; nt < 4; nt++)
                acc[mt][nt] = __builtin_amdgcn_mfma_f32_16x16x32_bf16(af[mt], bf[nt], acc[mt][nt], 0, 0, 0);
        __syncthreads();
    }

    // bias
    float bias_v[4][4];
    #pragma unroll
    for (int mt = 0; mt < 4; mt++)
        #pragma unroll
        for (int r = 0; r < 4; r++)
            bias_v[mt][r] = ball[m0 + wm*64 + mt*16 + quad*4 + r];

    bf16* sEb = (bf16*)sE;
    if (my < 4) {
        // transposed epilogue: sE[n][m], then rows -> qT/kT [l][c]
        #pragma unroll
        for (int mt = 0; mt < 4; mt++)
            #pragma unroll
            for (int nt = 0; nt < 4; nt++)
                #pragma unroll
                for (int r = 0; r < 4; r++)
                    sEb[(wn*64 + nt*16 + col)*136 + wm*64 + mt*16 + quad*4 + r] =
                        __float2bfloat16(acc[mt][nt][r] + bias_v[mt][r]);
        __syncthreads();
        bf16* dst = (my < 2) ? qT : kT;
        const int c0 = (my & 1) * 128;
        #pragma unroll
        for (int j = 0; j < 8; j++) {
            int idx = j*256 + t;
            int n = idx >> 4, c8 = (idx & 15) << 3;
            *(v8s*)(dst + (size_t)(n0 + n) * C + c0 + c8) = *(const v8s*)&sE[n*136 + c8];
        }
    } else {
        // direct epilogue: sE[m][n], then rows -> vB [c][l]
        #pragma unroll
        for (int mt = 0; mt < 4; mt++)
            #pragma unroll
            for (int nt = 0; nt < 4; nt++)
                #pragma unroll
                for (int r = 0; r < 4; r++)
                    sEb[(wm*64 + mt*16 + quad*4 + r)*136 + wn*64 + nt*16 + col] =
                        __float2bfloat16(acc[mt][nt][r] + bias_v[mt][r]);
        __syncthreads();
        const int c0 = (my - 4) * 128;
        #pragma unroll
        for (int j = 0; j < 8; j++) {
            int idx = j*256 + t;
            int m = idx >> 4, n8 = (idx & 15) << 3;
            *(v8s*)(vB + (size_t)(c0 + m) * L + n0 + n8) = *(const v8s*)&sE[m*136 + n8];
        }
    }
}

// ---------------------------------------------------------------------------
// Output GEMM: out[512][L] = Wob[512][256] . aoT[L][256]^T + bo, * mask. fp32 out.
// ---------------------------------------------------------------------------
__global__ __launch_bounds__(256) void out_gemm(
    const bf16* __restrict__ A, const bf16* __restrict__ B,
    const float* __restrict__ bo, const float* __restrict__ mask,
    float* __restrict__ out)
{
    __shared__ short sA[128*32];
    __shared__ short sB[128*32];

    const int t    = threadIdx.x;
    const int lane = t & 63;
    const int w    = t >> 6;
    const int wm   = w & 1, wn = w >> 1;
    const int col  = lane & 15, quad = lane >> 4;
    const int n0   = blockIdx.x * 128;
    const int m0   = blockIdx.y * 128;

    v4f acc[4][4];
    #pragma unroll
    for (int i = 0; i < 4; i++)
        #pragma unroll
        for (int j = 0; j < 4; j++) acc[i][j] = (v4f){0.f,0.f,0.f,0.f};

    for (int k0 = 0; k0 < C; k0 += 32) {
        #pragma unroll
        for (int j = 0; j < 2; j++) {
            int idx = j*256 + t;
            int m = idx >> 2, k8 = (idx & 3) << 3;
            ldst16(&sA[idx*8], A + (size_t)(m0 + m) * C + k0 + k8);
        }
        #pragma unroll
        for (int j = 0; j < 2; j++) {
            int idx = j*256 + t;
            int n = idx >> 2, k8 = (idx & 3) << 3;
            ldst16(&sB[idx*8], B + (size_t)(n0 + n) * C + k0 + k8);
        }
        __syncthreads();
        v8s af[4], bf[4];
        #pragma unroll
        for (int mt = 0; mt < 4; mt++)
            af[mt] = *(const v8s*)&sA[(wm*64 + mt*16 + col)*32 + quad*8];
        #pragma unroll
        for (int nt = 0; nt < 4; nt++)
            bf[nt] = *(const v8s*)&sB[(wn*64 + nt*16 + col)*32 + quad*8];
        #pragma unroll
        for (int mt = 0; mt < 4; mt++)
            #pragma unroll
            for (int nt = 0; nt < 4; nt++)
                acc[mt][nt] = __builtin_amdgcn_mfma_f32_16x16x32_bf16(af[mt], bf[nt], acc[mt][nt], 0, 0, 0);
        __syncthreads();
    }

    float bias_v[4];
    #pragma unroll
    for (int mt = 0; mt < 4; mt++)
        bias_v[mt] = 0.f;
    #pragma unroll
    for (int mt = 0; mt < 4; mt++) {
        #pragma unroll
        for (int r = 0; r < 4; r++) {
            int m = m0 + wm*64 + mt*16 + quad*4 + r;
            float bb = bo[m];
            #pragma unroll
            for (int nt = 0; nt < 4; nt++) {
                int n = n0 + wn*64 + nt*16 + col;
                out[(size_t)m * L + n] = (acc[mt][nt][r] + bb) * mask[n];
            }
        }
    }
}

// ---------------------------------------------------------------------------
// Flash-style sliding-window attention (unchanged core from round 2).
// Output now: aoT bf16 [L][C] via packed 8B stores.
// ---------------------------------------------------------------------------
__global__ __launch_bounds__(256, 2) void attn_mfma(
    const bf16* __restrict__ qT, const bf16* __restrict__ kT,
    const bf16* __restrict__ vB, const float* __restrict__ mask,
    bf16* __restrict__ aoT)
{
    __shared__ short sK [64*264];   // [key][c]   33.8 KB
    __shared__ short sVt[256*72];   // [c][key]   36.9 KB
    __shared__ short sP [4][16*72]; // per-wave P [q][key]  9.2 KB

    const int t    = threadIdx.x;
    const int w    = t >> 6;
    const int lane = t & 63;
    const int col  = lane & 15;
    const int quad = lane >> 4;
    const int p0   = blockIdx.x * 64;
    const int abase = p0 - 256;

    v8s qf[8];
    {
        const short* qp = (const short*)qT + (size_t)(p0 + w*16 + col) * C + quad*8;
        #pragma unroll
        for (int ks = 0; ks < 8; ks++) qf[ks] = *(const v8s*)(qp + ks*32);
    }

    v4f oacc[16];
    #pragma unroll
    for (int i = 0; i < 16; i++) oacc[i] = (v4f){0.f, 0.f, 0.f, 0.f};
    float mrow[4] = {-1e30f, -1e30f, -1e30f, -1e30f};
    float lrow[4] = {0.f, 0.f, 0.f, 0.f};

    for (int ch = 0; ch < 9; ch++) {
        const int a0 = abase + ch*64;
        __syncthreads();
        #pragma unroll
        for (int i = 0; i < 8; i++) {
            int idx = i*256 + t;
            int r = idx >> 5, cb = (idx & 31) << 3;
            int a = a0 + r;
            v8s val = {0,0,0,0,0,0,0,0};
            if (a >= 0 && a < L)
                val = *(const v8s*)((const short*)kT + (size_t)a * C + cb);
            *(v8s*)&sK[r*264 + cb] = val;
        }
        if (a0 >= 0 && a0 + 63 < L) {
            #pragma unroll
            for (int i = 0; i < 8; i++) {
                int idx = i*256 + t;
                int c = idx >> 3, kb = (idx & 7) << 3;
                *(v8s*)&sVt[c*72 + kb] =
                    *(const v8s*)((const short*)vB + (size_t)c * L + a0 + kb);
            }
        } else {
            #pragma unroll
            for (int i = 0; i < 8; i++) {
                int idx = i*256 + t;
                int c = idx >> 3, kb = (idx & 7) << 3;
                v8s val;
                #pragma unroll
                for (int j = 0; j < 8; j++) {
                    int a = a0 + kb + j;
                    val[j] = (a >= 0 && a < L)
                        ? ((const short*)vB)[(size_t)c * L + a] : (short)0;
                }
                *(v8s*)&sVt[c*72 + kb] = val;
            }
        }
        __syncthreads();

        v4f e[4];
        #pragma unroll
        for (int nt = 0; nt < 4; nt++) {
            v4f acc = {0.f, 0.f, 0.f, 0.f};
            const short* kp = &sK[(nt*16 + col)*264 + quad*8];
            #pragma unroll
            for (int ks = 0; ks < 8; ks++) {
                v8s bfrag = *(const v8s*)(kp + ks*32);
                acc = __builtin_amdgcn_mfma_f32_16x16x32_bf16(qf[ks], bfrag, acc, 0, 0, 0);
            }
            e[nt] = acc;
        }

        float cmax[4] = {-1e30f, -1e30f, -1e30f, -1e30f};
        #pragma unroll
        for (int nt = 0; nt < 4; nt++) {
            int a  = a0 + nt*16 + col;
            int aa = ch*64 + nt*16 + col;
            float mval = (a >= 0 && a < L) ? mask[a] : 0.f;
            #pragma unroll
            for (int r = 0; r < 4; r++) {
                int rel = aa - (w*16 + quad*4 + r);
                bool valid = ((unsigned)rel < 512u) && (mval > 0.f);
                float ev = valid ? e[nt][r] * SCALE : -1e30f;
                e[nt][r] = ev;
                cmax[r] = fmaxf(cmax[r], ev);
            }
        }
        #pragma unroll
        for (int off = 1; off < 16; off <<= 1) {
            #pragma unroll
            for (int r = 0; r < 4; r++)
                cmax[r] = fmaxf(cmax[r], __shfl_xor(cmax[r], off));
        }

        float alpha[4];
        #pragma unroll
        for (int r = 0; r < 4; r++) {
            float mnew = fmaxf(mrow[r], cmax[r]);
            alpha[r] = __expf(mrow[r] - mnew);
            mrow[r] = mnew;
        }

        float psum[4] = {0.f, 0.f, 0.f, 0.f};
        bf16* sPw = (bf16*)sP[w];
        #pragma unroll
        for (int nt = 0; nt < 4; nt++) {
            #pragma unroll
            for (int r = 0; r < 4; r++) {
                float ev = e[nt][r];
                float p = (ev > -9e29f) ? __expf(ev - mrow[r]) : 0.f;
                psum[r] += p;
                sPw[(quad*4 + r)*72 + nt*16 + col] = __float2bfloat16(p);
            }
        }
        #pragma unroll
        for (int off = 1; off < 16; off <<= 1) {
            #pragma unroll
            for (int r = 0; r < 4; r++)
                psum[r] += __shfl_xor(psum[r], off);
        }
        #pragma unroll
        for (int r = 0; r < 4; r++) lrow[r] = lrow[r]*alpha[r] + psum[r];

        {
            int src = (col >> 2) << 4;
            float a0b = __shfl(alpha[0], src);
            float a1b = __shfl(alpha[1], src);
            float a2b = __shfl(alpha[2], src);
            float a3b = __shfl(alpha[3], src);
            int rr = col & 3;
            float aO = (rr == 0) ? a0b : (rr == 1) ? a1b : (rr == 2) ? a2b : a3b;
            #pragma unroll
            for (int i = 0; i < 16; i++) {
                oacc[i][0] *= aO; oacc[i][1] *= aO;
                oacc[i][2] *= aO; oacc[i][3] *= aO;
            }
        }

        {
            const short* sPws = (const short*)sP[w];
            v8s pf0 = *(const v8s*)&sPws[col*72 + quad*8];
            v8s pf1 = *(const v8s*)&sPws[col*72 + quad*8 + 32];
            #pragma unroll
            for (int ct = 0; ct < 16; ct++) {
                const short* vp = &sVt[(ct*16 + col)*72 + quad*8];
                v8s vf0 = *(const v8s*)vp;
                v8s vf1 = *(const v8s*)(vp + 32);
                oacc[ct] = __builtin_amdgcn_mfma_f32_16x16x32_bf16(vf0, pf0, oacc[ct], 0, 0, 0);
                oacc[ct] = __builtin_amdgcn_mfma_f32_16x16x32_bf16(vf1, pf1, oacc[ct], 0, 0, 0);
            }
        }
    }

    {
        int src = (col >> 2) << 4;
        float l0b = __shfl(lrow[0], src);
        float l1b = __shfl(lrow[1], src);
        float l2b = __shfl(lrow[2], src);
        float l3b = __shfl(lrow[3], src);
        int rr = col & 3;
        float lO = (rr == 0) ? l0b : (rr == 1) ? l1b : (rr == 2) ? l2b : l3b;
        float inv = (lO > 0.f) ? 1.f / lO : 0.f;
        const int qg = p0 + w*16 + col;
        short* aorow = (short*)aoT + (size_t)qg * C;
        #pragma unroll
        for (int ct = 0; ct < 16; ct++) {
            v4s pk;
            #pragma unroll
            for (int r = 0; r < 4; r++)
                pk[r] = bfbits(fmaxf(oacc[ct][r] * inv, 0.f));
            *(v4s*)(aorow + ct*16 + quad*4) = pk;
        }
    }
}

extern "C" void kernel_launch(void* const* d_in, const int* in_sizes, int n_in,
                              void* d_out, int out_size, void* d_ws, size_t ws_size,
                              hipStream_t stream)
{
    const float* x1   = (const float*)d_in[0];
    const float* mask = (const float*)d_in[2];
    const float* Wq   = (const float*)d_in[3];
    const float* bq   = (const float*)d_in[4];
    const float* Wk   = (const float*)d_in[5];
    const float* bk   = (const float*)d_in[6];
    const float* Wv   = (const float*)d_in[7];
    const float* bv   = (const float*)d_in[8];
    const float* Wo   = (const float*)d_in[9];
    const float* bo   = (const float*)d_in[10];
    float* out = (float*)d_out;

    // ws: x1T bf16[L][512] | Wall bf16[768][512] | Wob bf16[512][256] |
    //     ball f32[768] | qT,kT bf16[L][256] | vB bf16[C][L] | aoT bf16[L][256]
    bf16* x1T  = (bf16*)d_ws;
    bf16* Wall = x1T + (size_t)L * QD;
    bf16* Wob  = Wall + 768*512;
    float* ball = (float*)(Wob + 512*256);
    bf16* qT   = (bf16*)(ball + 768);
    bf16* kT   = qT + (size_t)L * C;
    bf16* vB   = kT + (size_t)L * C;
    bf16* aoT  = vB + (size_t)L * C;

    dim3 blk(256);
    prep<<<dim3((768*512 + 512*256 + 768 + 255)/256), blk, 0, stream>>>(
        Wq, Wk, Wv, bq, bk, bv, Wo, Wall, Wob, ball);
    convt<<<dim3(L/64, QD/64), blk, 0, stream>>>(x1, (short*)x1T);
    qkv_gemm<<<dim3(L/128, 6), blk, 0, stream>>>(Wall, x1T, ball, qT, kT, vB);
    attn_mfma<<<dim3(L/64), blk, 0, stream>>>(qT, kT, vB, mask, aoT);
    out_gemm<<<dim3(L/128, 4), blk, 0, stream>>>(Wob, aoT, bo, mask, out);
}

// Round 4
// 291.970 us; speedup vs baseline: 7.6085x; 1.0430x over previous
//
#include <hip/hip_runtime.h>
#include <hip/hip_bf16.h>
#include <math.h>

#define L 32768
#define C 256
#define QD 512
#define SCALE (1.0f/16.0f)

typedef __hip_bfloat16 bf16;
typedef short v8s __attribute__((ext_vector_type(8)));
typedef short v4s __attribute__((ext_vector_type(4)));
typedef float v4f __attribute__((ext_vector_type(4)));

__device__ __forceinline__ void ldst16(void* lds, const void* g) {
    __builtin_amdgcn_global_load_lds(
        (const __attribute__((address_space(1))) unsigned int*)g,
        (__attribute__((address_space(3))) unsigned int*)lds, 16, 0, 0);
}
__device__ __forceinline__ short bfbits(float x) {
    bf16 h = __float2bfloat16(x);
    return *reinterpret_cast<short*>(&h);
}

// ---------------------------------------------------------------------------
// prep: pack Wq/Wk/Wv -> Wall bf16 [768][512]; Wo -> Wob bf16 [512][256];
// biases -> ball fp32 [768].
// ---------------------------------------------------------------------------
__global__ __launch_bounds__(256) void prep(
    const float* __restrict__ Wq, const float* __restrict__ Wk,
    const float* __restrict__ Wv, const float* __restrict__ bq,
    const float* __restrict__ bk, const float* __restrict__ bv,
    const float* __restrict__ Wo,
    bf16* __restrict__ Wall, bf16* __restrict__ Wob, float* __restrict__ ball)
{
    int i = blockIdx.x * 256 + threadIdx.x;
    if (i < 768*512) {
        int row = i >> 9, idx = i & 511;
        const float* src = row < 256 ? Wq : row < 512 ? Wk : Wv;
        Wall[i] = __float2bfloat16(src[(row & 255) * 512 + idx]);
    } else if (i < 768*512 + 512*256) {
        int j = i - 768*512;
        Wob[j] = __float2bfloat16(Wo[j]);
    } else if (i < 768*512 + 512*256 + 768) {
        int j = i - 768*512 - 512*256;
        ball[j] = j < 256 ? bq[j] : j < 512 ? bk[j - 256] : bv[j - 512];
    }
}

// ---------------------------------------------------------------------------
// convt: x1 fp32 [512][L] -> x1T bf16 [L][512], 64x64 tiles via LDS.
// ---------------------------------------------------------------------------
__global__ __launch_bounds__(256) void convt(
    const float* __restrict__ x, short* __restrict__ xT)
{
    __shared__ short st[64*72];
    const int t = threadIdx.x;
    const int l0 = blockIdx.x * 64, c0 = blockIdx.y * 64;
    #pragma unroll
    for (int i = 0; i < 2; i++) {
        int v = i*256 + t;
        int c = v >> 3, l8 = (v & 7) << 3;
        const float* p = x + (size_t)(c0 + c) * L + l0 + l8;
        float4 f0 = *(const float4*)p;
        float4 f1 = *(const float4*)(p + 4);
        bf16* stb = (bf16*)st;
        stb[(l8+0)*72 + c] = __float2bfloat16(f0.x);
        stb[(l8+1)*72 + c] = __float2bfloat16(f0.y);
        stb[(l8+2)*72 + c] = __float2bfloat16(f0.z);
        stb[(l8+3)*72 + c] = __float2bfloat16(f0.w);
        stb[(l8+4)*72 + c] = __float2bfloat16(f1.x);
        stb[(l8+5)*72 + c] = __float2bfloat16(f1.y);
        stb[(l8+6)*72 + c] = __float2bfloat16(f1.z);
        stb[(l8+7)*72 + c] = __float2bfloat16(f1.w);
    }
    __syncthreads();
    #pragma unroll
    for (int i = 0; i < 2; i++) {
        int v = i*256 + t;
        int l = v >> 3, c8 = (v & 7) << 3;
        *(v8s*)(xT + (size_t)(l0 + l) * QD + c0 + c8) = *(const v8s*)&st[l*72 + c8];
    }
}

// ---------------------------------------------------------------------------
// Fused QKV GEMM (m97-style): Y[768][L] = Wall[768][512] . x1T[L][512]^T.
// ---------------------------------------------------------------------------
__global__ __launch_bounds__(256) void qkv_gemm(
    const bf16* __restrict__ A, const bf16* __restrict__ B,
    const float* __restrict__ ball,
    bf16* __restrict__ qT, bf16* __restrict__ kT, bf16* __restrict__ vB)
{
    __shared__ short sA[128*32];
    __shared__ short sB[128*32];
    __shared__ short sE[128*136];

    const int t    = threadIdx.x;
    const int lane = t & 63;
    const int w    = t >> 6;
    const int wm   = w & 1, wn = w >> 1;
    const int col  = lane & 15, quad = lane >> 4;
    const int n0   = blockIdx.x * 128;
    const int my   = blockIdx.y;
    const int m0   = my * 128;

    v4f acc[4][4];
    #pragma unroll
    for (int i = 0; i < 4; i++)
        #pragma unroll
        for (int j = 0; j < 4; j++) acc[i][j] = (v4f){0.f,0.f,0.f,0.f};

    for (int k0 = 0; k0 < QD; k0 += 32) {
        #pragma unroll
        for (int j = 0; j < 2; j++) {
            int idx = j*256 + t;
            int m = idx >> 2, k8 = (idx & 3) << 3;
            ldst16(&sA[idx*8], A + (size_t)(m0 + m) * QD + k0 + k8);
        }
        #pragma unroll
        for (int j = 0; j < 2; j++) {
            int idx = j*256 + t;
            int n = idx >> 2, k8 = (idx & 3) << 3;
            ldst16(&sB[idx*8], B + (size_t)(n0 + n) * QD + k0 + k8);
        }
        __syncthreads();
        v8s af[4], bf[4];
        #pragma unroll
        for (int mt = 0; mt < 4; mt++)
            af[mt] = *(const v8s*)&sA[(wm*64 + mt*16 + col)*32 + quad*8];
        #pragma unroll
        for (int nt = 0; nt < 4; nt++)
            bf[nt] = *(const v8s*)&sB[(wn*64 + nt*16 + col)*32 + quad*8];
        #pragma unroll
        for (int mt = 0; mt < 4; mt++)
            #pragma unroll
            for (int nt = 0; nt < 4; nt++)
                acc[mt][nt] = __builtin_amdgcn_mfma_f32_16x16x32_bf16(af[mt], bf[nt], acc[mt][nt], 0, 0, 0);
        __syncthreads();
    }

    float bias_v[4][4];
    #pragma unroll
    for (int mt = 0; mt < 4; mt++)
        #pragma unroll
        for (int r = 0; r < 4; r++)
            bias_v[mt][r] = ball[m0 + wm*64 + mt*16 + quad*4 + r];

    bf16* sEb = (bf16*)sE;
    if (my < 4) {
        #pragma unroll
        for (int mt = 0; mt < 4; mt++)
            #pragma unroll
            for (int nt = 0; nt < 4; nt++)
                #pragma unroll
                for (int r = 0; r < 4; r++)
                    sEb[(wn*64 + nt*16 + col)*136 + wm*64 + mt*16 + quad*4 + r] =
                        __float2bfloat16(acc[mt][nt][r] + bias_v[mt][r]);
        __syncthreads();
        bf16* dst = (my < 2) ? qT : kT;
        const int c0 = (my & 1) * 128;
        #pragma unroll
        for (int j = 0; j < 8; j++) {
            int idx = j*256 + t;
            int n = idx >> 4, c8 = (idx & 15) << 3;
            *(v8s*)(dst + (size_t)(n0 + n) * C + c0 + c8) = *(const v8s*)&sE[n*136 + c8];
        }
    } else {
        #pragma unroll
        for (int mt = 0; mt < 4; mt++)
            #pragma unroll
            for (int nt = 0; nt < 4; nt++)
                #pragma unroll
                for (int r = 0; r < 4; r++)
                    sEb[(wm*64 + mt*16 + quad*4 + r)*136 + wn*64 + nt*16 + col] =
                        __float2bfloat16(acc[mt][nt][r] + bias_v[mt][r]);
        __syncthreads();
        const int c0 = (my - 4) * 128;
        #pragma unroll
        for (int j = 0; j < 8; j++) {
            int idx = j*256 + t;
            int m = idx >> 4, n8 = (idx & 15) << 3;
            *(v8s*)(vB + (size_t)(c0 + m) * L + n0 + n8) = *(const v8s*)&sE[m*136 + n8];
        }
    }
}

// ---------------------------------------------------------------------------
// Output GEMM: out[512][L] = Wob[512][256].aoT[L][256]^T + bo, * mask.
// Epilogue staged through LDS fp32 for contiguous 512B row writes.
// ---------------------------------------------------------------------------
__global__ __launch_bounds__(256) void out_gemm(
    const bf16* __restrict__ A, const bf16* __restrict__ B,
    const float* __restrict__ bo, const float* __restrict__ mask,
    float* __restrict__ out)
{
    __shared__ short sA[128*32];
    __shared__ short sB[128*32];
    __shared__ float sEf[64*132];   // 33.8 KB

    const int t    = threadIdx.x;
    const int lane = t & 63;
    const int w    = t >> 6;
    const int wm   = w & 1, wn = w >> 1;
    const int col  = lane & 15, quad = lane >> 4;
    const int n0   = blockIdx.x * 128;
    const int m0   = blockIdx.y * 128;

    v4f acc[4][4];
    #pragma unroll
    for (int i = 0; i < 4; i++)
        #pragma unroll
        for (int j = 0; j < 4; j++) acc[i][j] = (v4f){0.f,0.f,0.f,0.f};

    for (int k0 = 0; k0 < C; k0 += 32) {
        #pragma unroll
        for (int j = 0; j < 2; j++) {
            int idx = j*256 + t;
            int m = idx >> 2, k8 = (idx & 3) << 3;
            ldst16(&sA[idx*8], A + (size_t)(m0 + m) * C + k0 + k8);
        }
        #pragma unroll
        for (int j = 0; j < 2; j++) {
            int idx = j*256 + t;
            int n = idx >> 2, k8 = (idx & 3) << 3;
            ldst16(&sB[idx*8], B + (size_t)(n0 + n) * C + k0 + k8);
        }
        __syncthreads();
        v8s af[4], bf[4];
        #pragma unroll
        for (int mt = 0; mt < 4; mt++)
            af[mt] = *(const v8s*)&sA[(wm*64 + mt*16 + col)*32 + quad*8];
        #pragma unroll
        for (int nt = 0; nt < 4; nt++)
            bf[nt] = *(const v8s*)&sB[(wn*64 + nt*16 + col)*32 + quad*8];
        #pragma unroll
        for (int mt = 0; mt < 4; mt++)
            #pragma unroll
            for (int nt = 0; nt < 4; nt++)
                acc[mt][nt] = __builtin_amdgcn_mfma_f32_16x16x32_bf16(af[mt], bf[nt], acc[mt][nt], 0, 0, 0);
        __syncthreads();
    }

    #pragma unroll
    for (int half = 0; half < 2; half++) {
        if (wm == half) {
            #pragma unroll
            for (int mt = 0; mt < 4; mt++) {
                #pragma unroll
                for (int r = 0; r < 4; r++) {
                    float bb = bo[m0 + half*64 + mt*16 + quad*4 + r];
                    #pragma unroll
                    for (int nt = 0; nt < 4; nt++)
                        sEf[(mt*16 + quad*4 + r)*132 + wn*64 + nt*16 + col] =
                            acc[mt][nt][r] + bb;
                }
            }
        }
        __syncthreads();
        #pragma unroll
        for (int j = 0; j < 8; j++) {
            int idx = j*256 + t;
            int row = idx >> 5, s4 = (idx & 31) << 2;
            float4 vv = *(const float4*)&sEf[row*132 + s4];
            float4 mk = *(const float4*)&mask[n0 + s4];
            vv.x *= mk.x; vv.y *= mk.y; vv.z *= mk.z; vv.w *= mk.w;
            *(float4*)&out[(size_t)(m0 + half*64 + row) * L + n0 + s4] = vv;
        }
        __syncthreads();
    }
}

// ---------------------------------------------------------------------------
// Flash-style sliding-window attention v2: 128 queries/block, 512 threads
// (8 waves x 16q), 10 key-chunks of 64 covering [p0-256, p0+384),
// register-prefetch double buffering, XCD-swizzled p-tiles.
// ---------------------------------------------------------------------------
__device__ __forceinline__ void load_chunk(
    const short* __restrict__ kT, const short* __restrict__ vB,
    int a0, int t, v8s kreg[4], v8s vreg[4])
{
    #pragma unroll
    for (int j = 0; j < 4; j++) {
        int idx = j*512 + t;
        int r = idx >> 5, s = idx & 31;
        int a = a0 + r;
        v8s kv = {0,0,0,0,0,0,0,0};
        if (a >= 0 && a < L) kv = *(const v8s*)(kT + (size_t)a * C + s*8);
        kreg[j] = kv;
    }
    if (a0 >= 0 && a0 + 63 < L) {
        #pragma unroll
        for (int j = 0; j < 4; j++) {
            int idx = j*512 + t;
            int c = idx >> 3, s = idx & 7;
            vreg[j] = *(const v8s*)(vB + (size_t)c * L + a0 + s*8);
        }
    } else {
        #pragma unroll
        for (int j = 0; j < 4; j++) {
            int idx = j*512 + t;
            int c = idx >> 3, s = idx & 7;
            v8s val;
            #pragma unroll
            for (int e2 = 0; e2 < 8; e2++) {
                int a = a0 + s*8 + e2;
                val[e2] = (a >= 0 && a < L) ? vB[(size_t)c * L + a] : (short)0;
            }
            vreg[j] = val;
        }
    }
}

__device__ __forceinline__ void store_chunk(
    short* __restrict__ sK, short* __restrict__ sVt, int t,
    const v8s kreg[4], const v8s vreg[4])
{
    #pragma unroll
    for (int j = 0; j < 4; j++) {
        int idx = j*512 + t;
        int r = idx >> 5, s = idx & 31;
        *(v8s*)&sK[r*264 + s*8] = kreg[j];
    }
    #pragma unroll
    for (int j = 0; j < 4; j++) {
        int idx = j*512 + t;
        int c = idx >> 3, s = idx & 7;
        *(v8s*)&sVt[c*72 + s*8] = vreg[j];
    }
}

__global__ __launch_bounds__(512, 2) void attn_mfma(
    const bf16* __restrict__ qT, const bf16* __restrict__ kT,
    const bf16* __restrict__ vB, const float* __restrict__ mask,
    bf16* __restrict__ aoT)
{
    __shared__ short sK [64*264];   // 33.8 KB
    __shared__ short sVt[256*72];   // 36.9 KB
    __shared__ short sP [8][16*72]; // 18.4 KB

    const int t    = threadIdx.x;
    const int w    = t >> 6;
    const int lane = t & 63;
    const int col  = lane & 15;
    const int quad = lane >> 4;
    const int bx   = blockIdx.x;
    const int tile = ((bx & 7) << 5) | (bx >> 3);   // XCD-contiguous p ranges
    const int p0   = tile * 128;
    const int abase = p0 - 256;

    v8s qf[8];
    {
        const short* qp = (const short*)qT + (size_t)(p0 + w*16 + col) * C + quad*8;
        #pragma unroll
        for (int ks = 0; ks < 8; ks++) qf[ks] = *(const v8s*)(qp + ks*32);
    }

    v4f oacc[16];
    #pragma unroll
    for (int i = 0; i < 16; i++) oacc[i] = (v4f){0.f, 0.f, 0.f, 0.f};
    float mrow[4] = {-1e30f, -1e30f, -1e30f, -1e30f};
    float lrow[4] = {0.f, 0.f, 0.f, 0.f};

    v8s kreg[4], vreg[4];
    load_chunk((const short*)kT, (const short*)vB, abase, t, kreg, vreg);
    store_chunk(sK, sVt, t, kreg, vreg);
    __syncthreads();

    for (int ch = 0; ch < 10; ch++) {
        const int a0 = abase + ch*64;
        const bool pf = (ch < 9);
        if (pf)
            load_chunk((const short*)kT, (const short*)vB, a0 + 64, t, kreg, vreg);

        // ---- QK^T ----
        v4f e[4];
        #pragma unroll
        for (int nt = 0; nt < 4; nt++) {
            v4f acc = {0.f, 0.f, 0.f, 0.f};
            const short* kp = &sK[(nt*16 + col)*264 + quad*8];
            #pragma unroll
            for (int ks = 0; ks < 8; ks++) {
                v8s bfrag = *(const v8s*)(kp + ks*32);
                acc = __builtin_amdgcn_mfma_f32_16x16x32_bf16(qf[ks], bfrag, acc, 0, 0, 0);
            }
            e[nt] = acc;
        }

        // ---- mask + scale + row max ----
        float cmax[4] = {-1e30f, -1e30f, -1e30f, -1e30f};
        #pragma unroll
        for (int nt = 0; nt < 4; nt++) {
            int a  = a0 + nt*16 + col;
            int aa = ch*64 + nt*16 + col;
            float mval = (a >= 0 && a < L) ? mask[a] : 0.f;
            #pragma unroll
            for (int r = 0; r < 4; r++) {
                int rel = aa - (w*16 + quad*4 + r);
                bool valid = ((unsigned)rel < 512u) && (mval > 0.f);
                float ev = valid ? e[nt][r] * SCALE : -1e30f;
                e[nt][r] = ev;
                cmax[r] = fmaxf(cmax[r], ev);
            }
        }
        #pragma unroll
        for (int off = 1; off < 16; off <<= 1) {
            #pragma unroll
            for (int r = 0; r < 4; r++)
                cmax[r] = fmaxf(cmax[r], __shfl_xor(cmax[r], off));
        }

        float alpha[4];
        #pragma unroll
        for (int r = 0; r < 4; r++) {
            float mnew = fmaxf(mrow[r], cmax[r]);
            alpha[r] = __expf(mrow[r] - mnew);
            mrow[r] = mnew;
        }

        // ---- P = exp(E - m), row sums, P -> wave-private LDS ----
        float psum[4] = {0.f, 0.f, 0.f, 0.f};
        bf16* sPw = (bf16*)sP[w];
        #pragma unroll
        for (int nt = 0; nt < 4; nt++) {
            #pragma unroll
            for (int r = 0; r < 4; r++) {
                float ev = e[nt][r];
                float p = (ev > -9e29f) ? __expf(ev - mrow[r]) : 0.f;
                psum[r] += p;
                sPw[(quad*4 + r)*72 + nt*16 + col] = __float2bfloat16(p);
            }
        }
        #pragma unroll
        for (int off = 1; off < 16; off <<= 1) {
            #pragma unroll
            for (int r = 0; r < 4; r++)
                psum[r] += __shfl_xor(psum[r], off);
        }
        #pragma unroll
        for (int r = 0; r < 4; r++) lrow[r] = lrow[r]*alpha[r] + psum[r];

        // ---- rescale O ----
        {
            int src = (col >> 2) << 4;
            float a0b = __shfl(alpha[0], src);
            float a1b = __shfl(alpha[1], src);
            float a2b = __shfl(alpha[2], src);
            float a3b = __shfl(alpha[3], src);
            int rr = col & 3;
            float aO = (rr == 0) ? a0b : (rr == 1) ? a1b : (rr == 2) ? a2b : a3b;
            #pragma unroll
            for (int i = 0; i < 16; i++) {
                oacc[i][0] *= aO; oacc[i][1] *= aO;
                oacc[i][2] *= aO; oacc[i][3] *= aO;
            }
        }

        // ---- PV ----
        {
            const short* sPws = (const short*)sP[w];
            v8s pf0 = *(const v8s*)&sPws[col*72 + quad*8];
            v8s pf1 = *(const v8s*)&sPws[col*72 + quad*8 + 32];
            #pragma unroll
            for (int ct = 0; ct < 16; ct++) {
                const short* vp = &sVt[(ct*16 + col)*72 + quad*8];
                v8s vf0 = *(const v8s*)vp;
                v8s vf1 = *(const v8s*)(vp + 32);
                oacc[ct] = __builtin_amdgcn_mfma_f32_16x16x32_bf16(vf0, pf0, oacc[ct], 0, 0, 0);
                oacc[ct] = __builtin_amdgcn_mfma_f32_16x16x32_bf16(vf1, pf1, oacc[ct], 0, 0, 0);
            }
        }

        if (pf) {
            __syncthreads();
            store_chunk(sK, sVt, t, kreg, vreg);
            __syncthreads();
        }
    }

    // ---- epilogue ----
    {
        int src = (col >> 2) << 4;
        float l0b = __shfl(lrow[0], src);
        float l1b = __shfl(lrow[1], src);
        float l2b = __shfl(lrow[2], src);
        float l3b = __shfl(lrow[3], src);
        int rr = col & 3;
        float lO = (rr == 0) ? l0b : (rr == 1) ? l1b : (rr == 2) ? l2b : l3b;
        float inv = (lO > 0.f) ? 1.f / lO : 0.f;
        const int qg = p0 + w*16 + col;
        short* aorow = (short*)aoT + (size_t)qg * C;
        #pragma unroll
        for (int ct = 0; ct < 16; ct++) {
            v4s pk;
            #pragma unroll
            for (int r = 0; r < 4; r++)
                pk[r] = bfbits(fmaxf(oacc[ct][r] * inv, 0.f));
            *(v4s*)(aorow + ct*16 + quad*4) = pk;
        }
    }
}

extern "C" void kernel_launch(void* const* d_in, const int* in_sizes, int n_in,
                              void* d_out, int out_size, void* d_ws, size_t ws_size,
                              hipStream_t stream)
{
    const float* x1   = (const float*)d_in[0];
    const float* mask = (const float*)d_in[2];
    const float* Wq   = (const float*)d_in[3];
    const float* bq   = (const float*)d_in[4];
    const float* Wk   = (const float*)d_in[5];
    const float* bk   = (const float*)d_in[6];
    const float* Wv   = (const float*)d_in[7];
    const float* bv   = (const float*)d_in[8];
    const float* Wo   = (const float*)d_in[9];
    const float* bo   = (const float*)d_in[10];
    float* out = (float*)d_out;

    bf16* x1T  = (bf16*)d_ws;
    bf16* Wall = x1T + (size_t)L * QD;
    bf16* Wob  = Wall + 768*512;
    float* ball = (float*)(Wob + 512*256);
    bf16* qT   = (bf16*)(ball + 768);
    bf16* kT   = qT + (size_t)L * C;
    bf16* vB   = kT + (size_t)L * C;
    bf16* aoT  = vB + (size_t)L * C;

    dim3 blk(256);
    prep<<<dim3((768*512 + 512*256 + 768 + 255)/256), blk, 0, stream>>>(
        Wq, Wk, Wv, bq, bk, bv, Wo, Wall, Wob, ball);
    convt<<<dim3(L/64, QD/64), blk, 0, stream>>>(x1, (short*)x1T);
    qkv_gemm<<<dim3(L/128, 6), blk, 0, stream>>>(Wall, x1T, ball, qT, kT, vB);
    attn_mfma<<<dim3(L/128), dim3(512), 0, stream>>>(qT, kT, vB, mask, aoT);
    out_gemm<<<dim3(L/128, 4), blk, 0, stream>>>(Wob, aoT, bo, mask, out);
}